// Round 10
// baseline (202.677 us; speedup 1.0000x reference)
//
#include <hip/hip_runtime.h>
#include <math.h>
#include <stdint.h>

#define LN_EPS 1e-5f
#define L2E 1.4426950408889634f

typedef __attribute__((ext_vector_type(8))) short short8;   // 8 bf16 (4 VGPRs)
typedef __attribute__((ext_vector_type(4))) float f32x4;

// ---------- bf16 pack/unpack (RNE) ----------
__device__ __forceinline__ uint32_t pack_bf2(float a, float b) {
  uint32_t ua = __float_as_uint(a);
  uint32_t ub = __float_as_uint(b);
  ua = (ua + 0x7fffu + ((ua >> 16) & 1u)) >> 16;
  ub = (ub + 0x7fffu + ((ub >> 16) & 1u)) & 0xffff0000u;
  return ua | ub;
}
__device__ __forceinline__ float2 unpack_bf2(uint32_t u) {
  return make_float2(__uint_as_float(u << 16), __uint_as_float(u & 0xffff0000u));
}
__device__ __forceinline__ uint16_t bf16_rne(float f) {
  uint32_t u = __float_as_uint(f);
  return (uint16_t)((u + 0x7fffu + ((u >> 16) & 1u)) >> 16);
}

// ---------- DPP sum over each 16-lane row (all lanes get the row sum) ----------
__device__ __forceinline__ float row16_sum(float x) {
  x += __int_as_float(__builtin_amdgcn_mov_dpp(__float_as_int(x), 0xB1, 0xF, 0xF, true));
  x += __int_as_float(__builtin_amdgcn_mov_dpp(__float_as_int(x), 0x4E, 0xF, 0xF, true));
  x += __int_as_float(__builtin_amdgcn_mov_dpp(__float_as_int(x), 0x124, 0xF, 0xF, true));
  x += __int_as_float(__builtin_amdgcn_mov_dpp(__float_as_int(x), 0x128, 0xF, 0xF, true));
  return x;
}

// ---------------- zero fill ----------------
__global__ void zero_kernel(int* __restrict__ p, int n) {
  int i = blockIdx.x * blockDim.x + threadIdx.x;
  if (i < n) p[i] = 0;
}

// ---------------- edge histogram + xb16 build (x rows as zero-padded bf16[32]) ------------
__global__ void prep_hist_kernel(const int* __restrict__ ei, int E, int N,
                                 int* __restrict__ cnt,
                                 const float* __restrict__ x, uint16_t* __restrict__ xb16) {
  int tid = blockIdx.x * blockDim.x + threadIdx.x;
  if (tid < N) {
    const float4* xf4 = (const float4*)x;
    float4 a = xf4[(size_t)tid * 2], b = xf4[(size_t)tid * 2 + 1];
    uint32_t* row = (uint32_t*)(xb16 + (size_t)tid * 32);
    row[0] = pack_bf2(a.x, a.y);
    row[1] = pack_bf2(a.z, a.w);
    row[2] = pack_bf2(b.x, b.y);
    row[3] = pack_bf2(b.z, b.w);
#pragma unroll
    for (int j = 4; j < 16; ++j) row[j] = 0;
  }
  if (tid < E + N) {
    int dst = (tid < E) ? ei[E + tid] : (tid - E);
    atomicAdd(&cnt[dst], 1);
  }
}

// per-thread segment sums + wave shfl scan; writes offs AND seeds cursor
__global__ __launch_bounds__(1024) void scan_kernel(const int* __restrict__ cnt,
                                                    int* __restrict__ offs,
                                                    int* __restrict__ cursor, int n) {
  __shared__ int wsum[16];
  int tid = threadIdx.x;
  int lane = tid & 63, w = tid >> 6;
  int PER = (n + 1023) >> 10;
  int base = tid * PER;
  int s = 0;
  for (int j = 0; j < PER; ++j) {
    int idx = base + j;
    s += (idx < n) ? cnt[idx] : 0;
  }
  int inc = s;
#pragma unroll
  for (int d = 1; d < 64; d <<= 1) {
    int t = __shfl_up(inc, d, 64);
    if (lane >= d) inc += t;
  }
  if (lane == 63) wsum[w] = inc;
  __syncthreads();
  int wpre = 0;
  for (int j = 0; j < w; ++j) wpre += wsum[j];
  int run = wpre + inc - s;
  for (int j = 0; j < PER; ++j) {
    int idx = base + j;
    if (idx < n) {
      offs[idx] = run;
      cursor[idx] = run;
      run += cnt[idx];
    }
  }
  if (tid == 1023) offs[n] = run;
}

// scatter + prep: blocks 0..63 -> Wtb (gemm2 A); 64..95 -> Wb1pad; 96 -> att1 scaled
__global__ void scatter_kernel(const int* __restrict__ ei, int E, int N,
                               int* __restrict__ cursor, int* __restrict__ esrc,
                               const float* __restrict__ Wl2, const float* __restrict__ Wr2,
                               uint16_t* __restrict__ Wtb,
                               const float* __restrict__ Wl1, uint16_t* __restrict__ Wb1pad,
                               const float* __restrict__ att1, float* __restrict__ att1s) {
  if (blockIdx.x < 64) {
    int idx = blockIdx.x * 256 + threadIdx.x;   // 64*256 == 256*64
    int c = idx >> 6, k = idx & 63;
    float v = (c < 128) ? Wl2[k * 128 + c] : Wr2[k * 128 + (c - 128)];
    Wtb[idx] = bf16_rne(v);
  } else if (blockIdx.x < 96) {
    int idx = (blockIdx.x - 64) * 256 + threadIdx.x;   // 0..8191 = ch*32 + k
    int ch = idx >> 5, k = idx & 31;
    Wb1pad[idx] = (k < 8) ? bf16_rne(Wl1[k * 256 + ch]) : (uint16_t)0;
  } else if (blockIdx.x == 96) {
    if (threadIdx.x < 256) att1s[threadIdx.x] = 0.4f * L2E * att1[threadIdx.x];
  }
  int e = blockIdx.x * blockDim.x + threadIdx.x;
  if (e >= E + N) return;
  int src, dst;
  if (e < E) { src = ei[e]; dst = ei[E + e]; }
  else       { src = e - E; dst = src; }
  int pos = atomicAdd(&cursor[dst], 1);
  esrc[pos] = src;
}

// ---------------- layer-2 linear via MFMA (unchanged, proven) ----------------
__global__ __launch_bounds__(256) void gemm2_mfma_kernel(
    const uint16_t* __restrict__ h1b,   // [N][64] bf16
    const uint16_t* __restrict__ Wtb,   // [256][64] bf16
    const float* __restrict__ bl, const float* __restrict__ br,
    uint32_t* __restrict__ xl2b, float* __restrict__ xr2, int N) {
  int lane = threadIdx.x & 63;
  int w = threadIdx.x >> 6;
  int c0 = w << 6;
  int l15 = lane & 15, l4 = lane >> 4;
  int node = (blockIdx.x << 4) + l15;
  int nodec = node < N ? node : N - 1;
  const short8* hrow = (const short8*)(h1b + (size_t)nodec * 64);
  short8 b0 = hrow[l4];
  short8 b1 = hrow[4 + l4];
  f32x4 acc[4] = {{0.f,0.f,0.f,0.f},{0.f,0.f,0.f,0.f},{0.f,0.f,0.f,0.f},{0.f,0.f,0.f,0.f}};
#pragma unroll
  for (int t = 0; t < 4; ++t) {
    int row = c0 + (t << 4) + l15;
    const short8* wrow = (const short8*)(Wtb + (size_t)row * 64);
    short8 a0 = wrow[l4];
    short8 a1 = wrow[4 + l4];
    acc[t] = __builtin_amdgcn_mfma_f32_16x16x32_bf16(a0, b0, acc[t], 0, 0, 0);
    acc[t] = __builtin_amdgcn_mfma_f32_16x16x32_bf16(a1, b1, acc[t], 0, 0, 0);
  }
  if (node >= N) return;
  if (c0 < 128) {
#pragma unroll
    for (int t = 0; t < 4; ++t) {
      int q0 = c0 + (t << 4) + (l4 << 2);
      float4 bb = *(const float4*)(bl + q0);
      uint2 pk;
      pk.x = pack_bf2(acc[t][0] + bb.x, acc[t][1] + bb.y);
      pk.y = pack_bf2(acc[t][2] + bb.z, acc[t][3] + bb.w);
      *(uint2*)(xl2b + (size_t)node * 64 + (q0 >> 1)) = pk;
    }
  } else {
#pragma unroll
    for (int t = 0; t < 4; ++t) {
      int q0 = (c0 - 128) + (t << 4) + (l4 << 2);
      float4 bb = *(const float4*)(br + q0);
      float4 v = make_float4(acc[t][0] + bb.x, acc[t][1] + bb.y,
                             acc[t][2] + bb.z, acc[t][3] + bb.w);
      *(float4*)(xr2 + (size_t)node * 128 + q0) = v;
    }
  }
}

// ---------------- attn layer 1 via MFMA edge-tiles + factored aggregation -----------------
// Per 16-edge tile: t[ch,e] = Wl x[e] + tb[ch] via 16 MFMA (K padded 8->32, zero tables).
// score_h(e) = sum_ch att^[ch]*(1.5 t + |t|)  (att^ = 0.4*log2e*att);  w = exp2(score).
// Aggregation factored: out = Wl*(sum_e w x[e]) + bl*den  (tb - xr cancels to bl).
__global__ __launch_bounds__(256) void attn1_mfma_kernel(
    const float* __restrict__ x,
    const float* __restrict__ Wl, const float* __restrict__ bl,
    const float* __restrict__ Wr, const float* __restrict__ br,
    const uint16_t* __restrict__ xb16, const uint16_t* __restrict__ Wb1pad,
    const float* __restrict__ att1s, const float* __restrict__ b1,
    const float* __restrict__ g, const float* __restrict__ be,
    const int* __restrict__ offs, const int* __restrict__ esrc,
    uint32_t* __restrict__ h1b, int N) {
  __shared__ float4   ltb[4 * 64];          // per-wave tb staging (acc-layout reads)
  __shared__ uint16_t lW[256 * 40];         // Wl tiles, row stride 40 bf16 (80B: 2-way banks)
  int lane = threadIdx.x & 63;
  int wid = threadIdx.x >> 6;
  int l15 = lane & 15, l4 = lane >> 4;

  // block-cooperative stage of Wb1pad into LDS (row = 32 bf16 -> stride-40 rows)
  {
    int row = threadIdx.x;   // 256 rows, one per thread
    const uint2* src = (const uint2*)(Wb1pad + (size_t)row * 32);
    uint2* dst = (uint2*)(lW + (size_t)row * 40);
#pragma unroll
    for (int j = 0; j < 8; ++j) dst[j] = src[j];
  }
  __syncthreads();

  int i = blockIdx.x * 4 + wid;
  if (i >= N) return;
  const float4* xf4 = (const float4*)x;

  // ---- prologue: xr = br + x@Wr (lane layout); tb = bl + xr; redistribute to acc layout ----
  float4 xa_ = xf4[(size_t)i * 2], xb_ = xf4[(size_t)i * 2 + 1];
  float xs0 = xa_.x, xs1 = xa_.y, xs2 = xa_.z, xs3 = xa_.w;
  float xs4 = xb_.x, xs5 = xb_.y, xs6 = xb_.z, xs7 = xb_.w;
  float4 xr = ((const float4*)br)[lane];
  {
    float xsv[8] = {xs0, xs1, xs2, xs3, xs4, xs5, xs6, xs7};
#pragma unroll
    for (int k = 0; k < 8; ++k) {
      float4 wr = ((const float4*)(Wr + k * 256))[lane];
      xr.x = fmaf(xsv[k], wr.x, xr.x);
      xr.y = fmaf(xsv[k], wr.y, xr.y);
      xr.z = fmaf(xsv[k], wr.z, xr.z);
      xr.w = fmaf(xsv[k], wr.w, xr.w);
    }
  }
  float4 bl4 = ((const float4*)bl)[lane];
  float4 tb4 = make_float4(bl4.x + xr.x, bl4.y + xr.y, bl4.z + xr.z, bl4.w + xr.w);
  ltb[wid * 64 + lane] = tb4;
  // same-wave LDS write->read; compiler inserts lgkmcnt wait
  float4 tbm[16];
#pragma unroll
  for (int m = 0; m < 16; ++m) tbm[m] = ltb[wid * 64 + 4 * m + l4];

  float den[4] = {0.f, 0.f, 0.f, 0.f};
  float2 xg[4] = {{0.f, 0.f}, {0.f, 0.f}, {0.f, 0.f}, {0.f, 0.f}};

  int beg = offs[i], end = offs[i + 1];
  int T = (end - beg + 15) >> 4;
  for (int tt = 0; tt < T; ++tt) {
    int eidx = beg + (tt << 4) + l15;
    bool valid = eidx < end;
    int ecl = valid ? eidx : end - 1;
    int s = esrc[ecl];
    short8 bf = *(const short8*)(xb16 + (size_t)s * 32 + (l4 << 3));
    float4 xf0 = xf4[(size_t)s * 2], xf1 = xf4[(size_t)s * 2 + 1];
    float2 xp = (l4 & 2) ? ((l4 & 1) ? make_float2(xf1.z, xf1.w) : make_float2(xf1.x, xf1.y))
                         : ((l4 & 1) ? make_float2(xf0.z, xf0.w) : make_float2(xf0.x, xf0.y));
#pragma unroll
    for (int h = 0; h < 4; ++h) {
      float sp = 0.f;
#pragma unroll
      for (int mm = 0; mm < 4; ++mm) {
        int m = 4 * h + mm;
        short8 af = *(const short8*)(lW + (size_t)(16 * m + l15) * 40 + (l4 << 3));
        f32x4 zz = {0.f, 0.f, 0.f, 0.f};
        f32x4 ac = __builtin_amdgcn_mfma_f32_16x16x32_bf16(af, bf, zz, 0, 0, 0);
        float4 tv = tbm[m];
        float t0 = ac[0] + tv.x, t1 = ac[1] + tv.y, t2 = ac[2] + tv.z, t3 = ac[3] + tv.w;
        float u0 = fmaf(1.5f, t0, fabsf(t0));
        float u1 = fmaf(1.5f, t1, fabsf(t1));
        float u2 = fmaf(1.5f, t2, fabsf(t2));
        float u3 = fmaf(1.5f, t3, fabsf(t3));
        float4 av = *(const float4*)(att1s + (m << 4) + (l4 << 2));
        sp = fmaf(av.x, u0, sp);
        sp = fmaf(av.y, u1, sp);
        sp = fmaf(av.z, u2, sp);
        sp = fmaf(av.w, u3, sp);
      }
      sp += __shfl_xor(sp, 16, 64);
      sp += __shfl_xor(sp, 32, 64);
      float w = valid ? exp2f(sp) : 0.f;
      den[h] += w;
      xg[h].x = fmaf(w, xp.x, xg[h].x);
      xg[h].y = fmaf(w, xp.y, xg[h].y);
    }
  }

  // ---- per-head reductions over the 16 edge-columns ----
#pragma unroll
  for (int h = 0; h < 4; ++h) {
    den[h] = row16_sum(den[h]);
    xg[h].x = row16_sum(xg[h].x);
    xg[h].y = row16_sum(xg[h].y);
  }

  // ---- out = Wl * xagg(head of this lane) / den + bl ----
  float4 v4 = make_float4(0.f, 0.f, 0.f, 0.f);
#pragma unroll
  for (int k = 0; k < 8; ++k) {
    int srcl = (k >> 1) << 4;
    float c0 = __shfl((k & 1) ? xg[0].y : xg[0].x, srcl, 64);
    float c1 = __shfl((k & 1) ? xg[1].y : xg[1].x, srcl, 64);
    float c2 = __shfl((k & 1) ? xg[2].y : xg[2].x, srcl, 64);
    float c3 = __shfl((k & 1) ? xg[3].y : xg[3].x, srcl, 64);
    float xsel = (l4 & 2) ? ((l4 & 1) ? c3 : c2) : ((l4 & 1) ? c1 : c0);
    float4 wlv = ((const float4*)(Wl + k * 256))[lane];
    v4.x = fmaf(wlv.x, xsel, v4.x);
    v4.y = fmaf(wlv.y, xsel, v4.y);
    v4.z = fmaf(wlv.z, xsel, v4.z);
    v4.w = fmaf(wlv.w, xsel, v4.w);
  }
  float dsel = (l4 & 2) ? ((l4 & 1) ? den[3] : den[2]) : ((l4 & 1) ? den[1] : den[0]);
  float inv = 1.0f / dsel;
  float v0 = fmaf(v4.x, inv, bl4.x);
  float v1 = fmaf(v4.y, inv, bl4.y);
  float v2 = fmaf(v4.z, inv, bl4.z);
  float v3 = fmaf(v4.w, inv, bl4.w);

  // ---- head mean + bias + LayerNorm + ReLU (lane = head l4, ch-in-head 4*l15+j) ----
  v0 += __shfl_xor(v0, 16, 64); v0 += __shfl_xor(v0, 32, 64);
  v1 += __shfl_xor(v1, 16, 64); v1 += __shfl_xor(v1, 32, 64);
  v2 += __shfl_xor(v2, 16, 64); v2 += __shfl_xor(v2, 32, 64);
  v3 += __shfl_xor(v3, 16, 64); v3 += __shfl_xor(v3, 32, 64);
  float4 b1q = ((const float4*)b1)[l15];
  v0 = 0.25f * v0 + b1q.x;
  v1 = 0.25f * v1 + b1q.y;
  v2 = 0.25f * v2 + b1q.z;
  v3 = 0.25f * v3 + b1q.w;
  float s1 = row16_sum(v0 + v1 + v2 + v3);
  float mu = s1 * (1.0f / 64.0f);
  float d0 = v0 - mu, d1 = v1 - mu, d2 = v2 - mu, d3 = v3 - mu;
  float s2 = row16_sum(d0 * d0 + d1 * d1 + d2 * d2 + d3 * d3);
  float rstd = rsqrtf(s2 * (1.0f / 64.0f) + LN_EPS);
  float4 gq = ((const float4*)g)[l15];
  float4 beq = ((const float4*)be)[l15];
  float y0 = fmaxf(fmaf(d0 * rstd, gq.x, beq.x), 0.f);
  float y1 = fmaxf(fmaf(d1 * rstd, gq.y, beq.y), 0.f);
  float y2 = fmaxf(fmaf(d2 * rstd, gq.z, beq.z), 0.f);
  float y3 = fmaxf(fmaf(d3 * rstd, gq.w, beq.w), 0.f);
  if (lane < 16) {
    uint2 pk;
    pk.x = pack_bf2(y0, y1);
    pk.y = pack_bf2(y2, y3);
    *(uint2*)(h1b + (size_t)i * 32 + l15 * 2) = pk;
  }
}

// ---------------- layer 2 attn: one node per wave, 4 gathers in flight, fused pooling ------
__global__ __launch_bounds__(256) void attn2_kernel(
    const uint32_t* __restrict__ xl2b, const float* __restrict__ xr2,
    const float* __restrict__ att, const float* __restrict__ b2,
    const float* __restrict__ g, const float* __restrict__ be,
    const int* __restrict__ offs, const int* __restrict__ esrc,
    const int* __restrict__ batch, float* __restrict__ pooled, int N) {
  int lane = threadIdx.x & 63;
  int i = blockIdx.x * (blockDim.x >> 6) + (threadIdx.x >> 6);
  if (i >= N) return;
  int cq = lane & 15;
  float2 attq = ((const float2*)att)[lane];
  float2 a4 = make_float2(0.4f * L2E * attq.x, 0.4f * L2E * attq.y);
  float2 xrq = ((const float2*)xr2)[(size_t)i * 64 + lane];
  float dA = 0.f, aA0 = 0.f, aA1 = 0.f;
  float dB = 0.f, aB0 = 0.f, aB1 = 0.f;
  int beg = offs[i], end = offs[i + 1];
  int p = beg;

#define EDGE2(U, DD, A0, A1)                                                   \
  {                                                                            \
    float2 e0 = unpack_bf2(U);                                                 \
    float t0 = e0.x + xrq.x, t1 = e0.y + xrq.y;                                \
    float u0 = fmaf(1.5f, t0, fabsf(t0));                                      \
    float u1 = fmaf(1.5f, t1, fabsf(t1));                                      \
    float sc = fmaf(a4.y, u1, a4.x * u0);                                      \
    sc = row16_sum(sc);                                                        \
    float wgt = exp2f(sc);                                                     \
    DD += wgt;                                                                 \
    A0 = fmaf(wgt, e0.x, A0); A1 = fmaf(wgt, e0.y, A1);                        \
  }

  for (; p + 3 < end; p += 4) {
    int s0 = esrc[p], s1 = esrc[p + 1], s2 = esrc[p + 2], s3 = esrc[p + 3];
    uint32_t u0 = xl2b[(uint32_t)s0 * 64u + lane];
    uint32_t u1 = xl2b[(uint32_t)s1 * 64u + lane];
    uint32_t u2 = xl2b[(uint32_t)s2 * 64u + lane];
    uint32_t u3 = xl2b[(uint32_t)s3 * 64u + lane];
    EDGE2(u0, dA, aA0, aA1)
    EDGE2(u1, dB, aB0, aB1)
    EDGE2(u2, dA, aA0, aA1)
    EDGE2(u3, dB, aB0, aB1)
  }
  for (; p < end; ++p) {
    int s0 = esrc[p];
    uint32_t u0 = xl2b[(uint32_t)s0 * 64u + lane];
    EDGE2(u0, dA, aA0, aA1)
  }
#undef EDGE2

  float inv = 1.0f / (dA + dB);
  float v0 = (aA0 + aB0) * inv;
  float v1 = (aA1 + aB1) * inv;
  v0 += __shfl_xor(v0, 16, 64); v0 += __shfl_xor(v0, 32, 64);
  v1 += __shfl_xor(v1, 16, 64); v1 += __shfl_xor(v1, 32, 64);
  float2 b2q = ((const float2*)b2)[cq];
  v0 = 0.25f * v0 + b2q.x;
  v1 = 0.25f * v1 + b2q.y;
  float s1 = row16_sum(v0 + v1);
  float mu = s1 * (1.0f / 32.0f);
  float d0 = v0 - mu, d1 = v1 - mu;
  float s2 = row16_sum(d0 * d0 + d1 * d1);
  float rstd = rsqrtf(s2 * (1.0f / 32.0f) + LN_EPS);
  float2 gq = ((const float2*)g)[cq];
  float2 beq = ((const float2*)be)[cq];
  float y0 = fmaxf(fmaf(d0 * rstd, gq.x, beq.x), 0.f);
  float y1 = fmaxf(fmaf(d1 * rstd, gq.y, beq.y), 0.f);
  if (lane < 16) {
    int gi = batch[i];
    atomicAdd(&pooled[gi * 32 + 2 * cq], y0);
    atomicAdd(&pooled[gi * 32 + 2 * cq + 1], y1);
  }
}

// ---------------- finalize: divide pooled sums by per-graph node count ----------------
__global__ void final_kernel(const float* __restrict__ pooled, const int* __restrict__ batch,
                             float* __restrict__ out, int N) {
  int gidx = blockIdx.x;
  int a = 0, b = N;
  while (a < b) { int m = (a + b) >> 1; if (batch[m] < gidx) a = m + 1; else b = m; }
  int lo = a;
  b = N;
  while (a < b) { int m = (a + b) >> 1; if (batch[m] < gidx + 1) a = m + 1; else b = m; }
  int cntv = a - lo;
  float inv = 1.0f / (float)(cntv > 0 ? cntv : 1);
  out[gidx * 32 + threadIdx.x] = pooled[gidx * 32 + threadIdx.x] * inv;
}

extern "C" void kernel_launch(void* const* d_in, const int* in_sizes, int n_in,
                              void* d_out, int out_size, void* d_ws, size_t ws_size,
                              hipStream_t stream) {
  const float* x    = (const float*)d_in[0];
  const int*   ei   = (const int*)d_in[1];
  const int*   batch= (const int*)d_in[2];
  const float* Wl1  = (const float*)d_in[3];
  const float* bl1  = (const float*)d_in[4];
  const float* Wr1  = (const float*)d_in[5];
  const float* br1  = (const float*)d_in[6];
  const float* att1 = (const float*)d_in[7];
  const float* b1   = (const float*)d_in[8];
  const float* ln1g = (const float*)d_in[9];
  const float* ln1b = (const float*)d_in[10];
  const float* Wl2  = (const float*)d_in[11];
  const float* bl2  = (const float*)d_in[12];
  const float* Wr2  = (const float*)d_in[13];
  const float* br2  = (const float*)d_in[14];
  const float* att2 = (const float*)d_in[15];
  const float* b2   = (const float*)d_in[16];
  const float* ln2g = (const float*)d_in[17];
  const float* ln2b = (const float*)d_in[18];

  int N = in_sizes[0] / 8;
  int E = in_sizes[1] / 2;
  int G = out_size / 32;

  char* ws = (char*)d_ws;
  size_t off = 0;
  auto alloc = [&](size_t bytes) -> void* {
    void* p = (void*)(ws + off);
    off += (bytes + 255) & ~(size_t)255;
    return p;
  };
  int*      cnt    = (int*)alloc((size_t)N * 4);
  float*    pooled = (float*)alloc((size_t)G * 32 * 4);   // contiguous with cnt: one zero pass
  int*      offs   = (int*)alloc((size_t)(N + 1) * 4);
  int*      cursor = (int*)alloc((size_t)N * 4);
  int*      esrc   = (int*)alloc((size_t)(E + N) * 4);
  uint16_t* xb16   = (uint16_t*)alloc((size_t)N * 32 * 2);   // x rows, bf16, k-padded to 32
  uint16_t* Wb1pad = (uint16_t*)alloc((size_t)256 * 32 * 2); // Wl1^T bf16, k-padded
  float*    att1s  = (float*)alloc((size_t)256 * 4);         // 0.4*log2e*att1
  uint32_t* h1b    = (uint32_t*)alloc((size_t)N * 64 * 2);   // 64 bf16/row
  uint16_t* Wtb    = (uint16_t*)alloc((size_t)256 * 64 * 2); // gemm2 A-tiles bf16
  uint32_t* xl2b   = (uint32_t*)alloc((size_t)N * 64 * 4);   // 128 bf16/row
  float*    xr2    = (float*)alloc((size_t)N * 128 * 4);

  int zero_ints = (int)(((char*)(pooled + (size_t)G * 32) - (char*)cnt) / 4);
  int tot = E + N;
  zero_kernel<<<(zero_ints + 255) / 256, 256, 0, stream>>>(cnt, zero_ints);
  prep_hist_kernel<<<(tot + 255) / 256, 256, 0, stream>>>(ei, E, N, cnt, x, xb16);
  scan_kernel<<<1, 1024, 0, stream>>>(cnt, offs, cursor, N);
  scatter_kernel<<<(tot + 255) / 256, 256, 0, stream>>>(ei, E, N, cursor, esrc,
                                                        Wl2, Wr2, Wtb, Wl1, Wb1pad,
                                                        att1, att1s);

  attn1_mfma_kernel<<<(N + 3) / 4, 256, 0, stream>>>(x, Wl1, bl1, Wr1, br1,
                                                     xb16, Wb1pad, att1s, b1,
                                                     ln1g, ln1b, offs, esrc, h1b, N);
  gemm2_mfma_kernel<<<(N + 15) / 16, 256, 0, stream>>>((const uint16_t*)h1b, Wtb, bl2, br2,
                                                       xl2b, xr2, N);
  attn2_kernel<<<(N + 3) / 4, 256, 0, stream>>>(xl2b, xr2, att2, b2, ln2g, ln2b,
                                                offs, esrc, batch, pooled, N);

  final_kernel<<<G, 32, 0, stream>>>(pooled, batch, (float*)d_out, N);
}

// Round 11
// 172.042 us; speedup vs baseline: 1.1781x; 1.1781x over previous
//
#include <hip/hip_runtime.h>
#include <math.h>
#include <stdint.h>

#define LN_EPS 1e-5f
#define L2E 1.4426950408889634f

typedef __attribute__((ext_vector_type(8))) short short8;   // 8 bf16 (4 VGPRs)
typedef __attribute__((ext_vector_type(4))) float f32x4;

// ---------- bf16 pack/unpack (RNE) ----------
__device__ __forceinline__ uint32_t pack_bf2(float a, float b) {
  uint32_t ua = __float_as_uint(a);
  uint32_t ub = __float_as_uint(b);
  ua = (ua + 0x7fffu + ((ua >> 16) & 1u)) >> 16;
  ub = (ub + 0x7fffu + ((ub >> 16) & 1u)) & 0xffff0000u;
  return ua | ub;
}
__device__ __forceinline__ float2 unpack_bf2(uint32_t u) {
  return make_float2(__uint_as_float(u << 16), __uint_as_float(u & 0xffff0000u));
}
__device__ __forceinline__ uint16_t bf16_rne(float f) {
  uint32_t u = __float_as_uint(f);
  return (uint16_t)((u + 0x7fffu + ((u >> 16) & 1u)) >> 16);
}

// ---------- DPP sum over each 16-lane row (all lanes get the row sum) ----------
__device__ __forceinline__ float row16_sum(float x) {
  x += __int_as_float(__builtin_amdgcn_mov_dpp(__float_as_int(x), 0xB1, 0xF, 0xF, true));
  x += __int_as_float(__builtin_amdgcn_mov_dpp(__float_as_int(x), 0x4E, 0xF, 0xF, true));
  x += __int_as_float(__builtin_amdgcn_mov_dpp(__float_as_int(x), 0x124, 0xF, 0xF, true));
  x += __int_as_float(__builtin_amdgcn_mov_dpp(__float_as_int(x), 0x128, 0xF, 0xF, true));
  return x;
}

// ---------------- zero fill ----------------
__global__ void zero_kernel(int* __restrict__ p, int n) {
  int i = blockIdx.x * blockDim.x + threadIdx.x;
  if (i < n) p[i] = 0;
}

// ---------------- layer-1 linear + edge histogram (fused; independent work) ----------------
__global__ __launch_bounds__(256) void gemm1_hist_kernel(
    const float* __restrict__ x,
    const float* __restrict__ Wl, const float* __restrict__ bl,
    const float* __restrict__ Wr, const float* __restrict__ br,
    uint32_t* __restrict__ xl1b, float* __restrict__ xr1, int N,
    const int* __restrict__ ei, int E, int* __restrict__ cnt) {
  int tid = threadIdx.x;
  int c2 = tid & 127;    // channel pair: 2*c2, 2*c2+1
  int which = tid >> 7;  // node sub-index within pair
  float wl0[8], wl1[8], wr0[8], wr1[8];
#pragma unroll
  for (int k = 0; k < 8; ++k) {
    wl0[k] = Wl[k * 256 + 2 * c2]; wl1[k] = Wl[k * 256 + 2 * c2 + 1];
    wr0[k] = Wr[k * 256 + 2 * c2]; wr1[k] = Wr[k * 256 + 2 * c2 + 1];
  }
  float bl0 = bl[2 * c2], bl1v = bl[2 * c2 + 1];
  float br0 = br[2 * c2], br1v = br[2 * c2 + 1];
  int npair = (N + 1) >> 1;
  for (int pr = blockIdx.x; pr < npair; pr += gridDim.x) {
    int n = pr * 2 + which;
    if (n >= N) continue;
    float4 xa = ((const float4*)x)[n * 2];
    float4 xb = ((const float4*)x)[n * 2 + 1];
    float xs[8] = {xa.x, xa.y, xa.z, xa.w, xb.x, xb.y, xb.z, xb.w};
    float al0 = bl0, al1 = bl1v, ar0 = br0, ar1 = br1v;
#pragma unroll
    for (int k = 0; k < 8; ++k) {
      al0 = fmaf(xs[k], wl0[k], al0); al1 = fmaf(xs[k], wl1[k], al1);
      ar0 = fmaf(xs[k], wr0[k], ar0); ar1 = fmaf(xs[k], wr1[k], ar1);
    }
    xl1b[(size_t)n * 128 + c2] = pack_bf2(al0, al1);
    ((float2*)xr1)[(size_t)n * 128 + c2] = make_float2(ar0, ar1);
  }
  // edge histogram (self-loops appended)
  int tot = E + N;
  for (int e = blockIdx.x * blockDim.x + tid; e < tot; e += gridDim.x * blockDim.x) {
    int dst = (e < E) ? ei[E + e] : (e - E);
    atomicAdd(&cnt[dst], 1);
  }
}

// per-thread segment sums + wave shfl scan; writes offs AND seeds cursor
__global__ __launch_bounds__(1024) void scan_kernel(const int* __restrict__ cnt,
                                                    int* __restrict__ offs,
                                                    int* __restrict__ cursor, int n) {
  __shared__ int wsum[16];
  int tid = threadIdx.x;
  int lane = tid & 63, w = tid >> 6;
  int PER = (n + 1023) >> 10;
  int base = tid * PER;
  int s = 0;
  for (int j = 0; j < PER; ++j) {
    int idx = base + j;
    s += (idx < n) ? cnt[idx] : 0;
  }
  int inc = s;
#pragma unroll
  for (int d = 1; d < 64; d <<= 1) {
    int t = __shfl_up(inc, d, 64);
    if (lane >= d) inc += t;
  }
  if (lane == 63) wsum[w] = inc;
  __syncthreads();
  int wpre = 0;
  for (int j = 0; j < w; ++j) wpre += wsum[j];
  int run = wpre + inc - s;   // exclusive prefix for this thread's segment
  for (int j = 0; j < PER; ++j) {
    int idx = base + j;
    if (idx < n) {
      offs[idx] = run;
      cursor[idx] = run;
      run += cnt[idx];
    }
  }
  if (tid == 1023) offs[n] = run;
}

// scatter + Wt prep (blocks [0,64) also transpose Wl2|Wr2 -> Wt[256][64] bf16)
__global__ void scatter_kernel(const int* __restrict__ ei, int E, int N,
                               int* __restrict__ cursor, int* __restrict__ esrc,
                               const float* __restrict__ Wl2, const float* __restrict__ Wr2,
                               uint16_t* __restrict__ Wtb) {
  if (blockIdx.x < 64) {
    int idx = blockIdx.x * 256 + threadIdx.x;   // 64*256 == 256*64
    int c = idx >> 6, k = idx & 63;
    float v = (c < 128) ? Wl2[k * 128 + c] : Wr2[k * 128 + (c - 128)];
    Wtb[idx] = bf16_rne(v);
  }
  int e = blockIdx.x * blockDim.x + threadIdx.x;
  if (e >= E + N) return;
  int src, dst;
  if (e < E) { src = ei[e]; dst = ei[E + e]; }
  else       { src = e - E; dst = src; }
  int pos = atomicAdd(&cursor[dst], 1);
  esrc[pos] = src;
}

// ---------------- layer-2 linear via MFMA ----------------
__global__ __launch_bounds__(256) void gemm2_mfma_kernel(
    const uint16_t* __restrict__ h1b,   // [N][64] bf16
    const uint16_t* __restrict__ Wtb,   // [256][64] bf16
    const float* __restrict__ bl, const float* __restrict__ br,
    uint32_t* __restrict__ xl2b, float* __restrict__ xr2, int N) {
  int lane = threadIdx.x & 63;
  int w = threadIdx.x >> 6;
  int c0 = w << 6;
  int l15 = lane & 15, l4 = lane >> 4;
  int node = (blockIdx.x << 4) + l15;
  int nodec = node < N ? node : N - 1;
  const short8* hrow = (const short8*)(h1b + (size_t)nodec * 64);
  short8 b0 = hrow[l4];
  short8 b1 = hrow[4 + l4];
  f32x4 acc[4] = {{0.f,0.f,0.f,0.f},{0.f,0.f,0.f,0.f},{0.f,0.f,0.f,0.f},{0.f,0.f,0.f,0.f}};
#pragma unroll
  for (int t = 0; t < 4; ++t) {
    int row = c0 + (t << 4) + l15;
    const short8* wrow = (const short8*)(Wtb + (size_t)row * 64);
    short8 a0 = wrow[l4];
    short8 a1 = wrow[4 + l4];
    acc[t] = __builtin_amdgcn_mfma_f32_16x16x32_bf16(a0, b0, acc[t], 0, 0, 0);
    acc[t] = __builtin_amdgcn_mfma_f32_16x16x32_bf16(a1, b1, acc[t], 0, 0, 0);
  }
  if (node >= N) return;
  if (c0 < 128) {
#pragma unroll
    for (int t = 0; t < 4; ++t) {
      int q0 = c0 + (t << 4) + (l4 << 2);
      float4 bb = *(const float4*)(bl + q0);
      uint2 pk;
      pk.x = pack_bf2(acc[t][0] + bb.x, acc[t][1] + bb.y);
      pk.y = pack_bf2(acc[t][2] + bb.z, acc[t][3] + bb.w);
      *(uint2*)(xl2b + (size_t)node * 64 + (q0 >> 1)) = pk;
    }
  } else {
#pragma unroll
    for (int t = 0; t < 4; ++t) {
      int q0 = (c0 - 128) + (t << 4) + (l4 << 2);
      float4 bb = *(const float4*)(br + q0);
      float4 v = make_float4(acc[t][0] + bb.x, acc[t][1] + bb.y,
                             acc[t][2] + bb.z, acc[t][3] + bb.w);
      *(float4*)(xr2 + (size_t)node * 128 + q0) = v;
    }
  }
}

// ---------------- attn layer 1: one node per wave, 4-deep gather, DPP reduce, exp2 --------
// score: att.lrelu(t) = sum (0.4*L2E*att_c)*(1.5*t_c + |t_c|)   [lrelu = 0.6t + 0.4|t|]
__global__ __launch_bounds__(256) void attn1_kernel(
    const uint32_t* __restrict__ xl1b, const float* __restrict__ xr1,
    const float* __restrict__ att, const float* __restrict__ b1,
    const float* __restrict__ g, const float* __restrict__ be,
    const int* __restrict__ offs, const int* __restrict__ esrc,
    uint32_t* __restrict__ h1b, int N) {
  int lane = threadIdx.x & 63;
  int i = blockIdx.x * (blockDim.x >> 6) + (threadIdx.x >> 6);
  if (i >= N) return;
  int cq = lane & 15;
  const uint2* xlb = (const uint2*)xl1b;  // row = 64 uint2 (256 bf16)
  float4 attq = ((const float4*)att)[lane];
  float4 a4 = make_float4(0.4f * L2E * attq.x, 0.4f * L2E * attq.y,
                          0.4f * L2E * attq.z, 0.4f * L2E * attq.w);
  float4 xrq = ((const float4*)xr1)[(size_t)i * 64 + lane];
  float dA = 0.f, aA0 = 0.f, aA1 = 0.f, aA2 = 0.f, aA3 = 0.f;
  float dB = 0.f, aB0 = 0.f, aB1 = 0.f, aB2 = 0.f, aB3 = 0.f;
  int beg = offs[i], end = offs[i + 1];
  int p = beg;

#define EDGE1(U, DD, A0, A1, A2, A3)                                           \
  {                                                                            \
    float2 e0 = unpack_bf2(U.x), e1 = unpack_bf2(U.y);                         \
    float t0 = e0.x + xrq.x, t1 = e0.y + xrq.y;                                \
    float t2 = e1.x + xrq.z, t3 = e1.y + xrq.w;                                \
    float u0 = fmaf(1.5f, t0, fabsf(t0));                                      \
    float u1 = fmaf(1.5f, t1, fabsf(t1));                                      \
    float u2 = fmaf(1.5f, t2, fabsf(t2));                                      \
    float u3 = fmaf(1.5f, t3, fabsf(t3));                                      \
    float sc = a4.x * u0;                                                      \
    sc = fmaf(a4.y, u1, sc);                                                   \
    sc = fmaf(a4.z, u2, sc);                                                   \
    sc = fmaf(a4.w, u3, sc);                                                   \
    sc = row16_sum(sc);                                                        \
    float wgt = exp2f(sc);                                                     \
    DD += wgt;                                                                 \
    A0 = fmaf(wgt, e0.x, A0); A1 = fmaf(wgt, e0.y, A1);                        \
    A2 = fmaf(wgt, e1.x, A2); A3 = fmaf(wgt, e1.y, A3);                        \
  }

  for (; p + 3 < end; p += 4) {
    int s0 = esrc[p], s1 = esrc[p + 1], s2 = esrc[p + 2], s3 = esrc[p + 3];
    uint2 u0 = xlb[(uint32_t)s0 * 64u + lane];
    uint2 u1 = xlb[(uint32_t)s1 * 64u + lane];
    uint2 u2 = xlb[(uint32_t)s2 * 64u + lane];
    uint2 u3 = xlb[(uint32_t)s3 * 64u + lane];
    EDGE1(u0, dA, aA0, aA1, aA2, aA3)
    EDGE1(u1, dB, aB0, aB1, aB2, aB3)
    EDGE1(u2, dA, aA0, aA1, aA2, aA3)
    EDGE1(u3, dB, aB0, aB1, aB2, aB3)
  }
  for (; p < end; ++p) {
    int s0 = esrc[p];
    uint2 u0 = xlb[(uint32_t)s0 * 64u + lane];
    EDGE1(u0, dA, aA0, aA1, aA2, aA3)
  }
#undef EDGE1

  float inv = 1.0f / (dA + dB);
  float v0 = (aA0 + aB0) * inv;
  float v1 = (aA1 + aB1) * inv;
  float v2 = (aA2 + aB2) * inv;
  float v3 = (aA3 + aB3) * inv;
  // mean over 4 heads (lanes differing in bits 4,5)
  v0 += __shfl_xor(v0, 16, 64); v0 += __shfl_xor(v0, 32, 64);
  v1 += __shfl_xor(v1, 16, 64); v1 += __shfl_xor(v1, 32, 64);
  v2 += __shfl_xor(v2, 16, 64); v2 += __shfl_xor(v2, 32, 64);
  v3 += __shfl_xor(v3, 16, 64); v3 += __shfl_xor(v3, 32, 64);
  float4 b1q = ((const float4*)b1)[cq];
  v0 = 0.25f * v0 + b1q.x;
  v1 = 0.25f * v1 + b1q.y;
  v2 = 0.25f * v2 + b1q.z;
  v3 = 0.25f * v3 + b1q.w;
  // LayerNorm over 64 channels (16 lanes x 4; head groups hold identical copies)
  float s1 = row16_sum(v0 + v1 + v2 + v3);
  float mu = s1 * (1.0f / 64.0f);
  float d0 = v0 - mu, d1 = v1 - mu, d2 = v2 - mu, d3 = v3 - mu;
  float s2 = row16_sum(d0 * d0 + d1 * d1 + d2 * d2 + d3 * d3);
  float rstd = rsqrtf(s2 * (1.0f / 64.0f) + LN_EPS);
  float4 gq = ((const float4*)g)[cq];
  float4 beq = ((const float4*)be)[cq];
  float y0 = fmaxf(fmaf(d0 * rstd, gq.x, beq.x), 0.f);
  float y1 = fmaxf(fmaf(d1 * rstd, gq.y, beq.y), 0.f);
  float y2 = fmaxf(fmaf(d2 * rstd, gq.z, beq.z), 0.f);
  float y3 = fmaxf(fmaf(d3 * rstd, gq.w, beq.w), 0.f);
  if (lane < 16) {
    uint2 pk;
    pk.x = pack_bf2(y0, y1);
    pk.y = pack_bf2(y2, y3);
    *(uint2*)(h1b + (size_t)i * 32 + cq * 2) = pk;   // [N][64] bf16
  }
}

// ---------------- layer 2 attn: one node per wave, 4-deep gather ----------------
__global__ __launch_bounds__(256) void attn2_kernel(
    const uint32_t* __restrict__ xl2b, const float* __restrict__ xr2,
    const float* __restrict__ att, const float* __restrict__ b2,
    const float* __restrict__ g, const float* __restrict__ be,
    const int* __restrict__ offs, const int* __restrict__ esrc,
    float* __restrict__ h2, int N) {
  int lane = threadIdx.x & 63;
  int i = blockIdx.x * (blockDim.x >> 6) + (threadIdx.x >> 6);
  if (i >= N) return;
  int cq = lane & 15;
  float2 attq = ((const float2*)att)[lane];
  float2 a4 = make_float2(0.4f * L2E * attq.x, 0.4f * L2E * attq.y);
  float2 xrq = ((const float2*)xr2)[(size_t)i * 64 + lane];
  float dA = 0.f, aA0 = 0.f, aA1 = 0.f;
  float dB = 0.f, aB0 = 0.f, aB1 = 0.f;
  int beg = offs[i], end = offs[i + 1];
  int p = beg;

#define EDGE2(U, DD, A0, A1)                                                   \
  {                                                                            \
    float2 e0 = unpack_bf2(U);                                                 \
    float t0 = e0.x + xrq.x, t1 = e0.y + xrq.y;                                \
    float u0 = fmaf(1.5f, t0, fabsf(t0));                                      \
    float u1 = fmaf(1.5f, t1, fabsf(t1));                                      \
    float sc = fmaf(a4.y, u1, a4.x * u0);                                      \
    sc = row16_sum(sc);                                                        \
    float wgt = exp2f(sc);                                                     \
    DD += wgt;                                                                 \
    A0 = fmaf(wgt, e0.x, A0); A1 = fmaf(wgt, e0.y, A1);                        \
  }

  for (; p + 3 < end; p += 4) {
    int s0 = esrc[p], s1 = esrc[p + 1], s2 = esrc[p + 2], s3 = esrc[p + 3];
    uint32_t u0 = xl2b[(uint32_t)s0 * 64u + lane];
    uint32_t u1 = xl2b[(uint32_t)s1 * 64u + lane];
    uint32_t u2 = xl2b[(uint32_t)s2 * 64u + lane];
    uint32_t u3 = xl2b[(uint32_t)s3 * 64u + lane];
    EDGE2(u0, dA, aA0, aA1)
    EDGE2(u1, dB, aB0, aB1)
    EDGE2(u2, dA, aA0, aA1)
    EDGE2(u3, dB, aB0, aB1)
  }
  for (; p < end; ++p) {
    int s0 = esrc[p];
    uint32_t u0 = xl2b[(uint32_t)s0 * 64u + lane];
    EDGE2(u0, dA, aA0, aA1)
  }
#undef EDGE2

  float inv = 1.0f / (dA + dB);
  float v0 = (aA0 + aB0) * inv;
  float v1 = (aA1 + aB1) * inv;
  v0 += __shfl_xor(v0, 16, 64); v0 += __shfl_xor(v0, 32, 64);
  v1 += __shfl_xor(v1, 16, 64); v1 += __shfl_xor(v1, 32, 64);
  float2 b2q = ((const float2*)b2)[cq];
  v0 = 0.25f * v0 + b2q.x;
  v1 = 0.25f * v1 + b2q.y;
  float s1 = row16_sum(v0 + v1);
  float mu = s1 * (1.0f / 32.0f);
  float d0 = v0 - mu, d1 = v1 - mu;
  float s2 = row16_sum(d0 * d0 + d1 * d1);
  float rstd = rsqrtf(s2 * (1.0f / 32.0f) + LN_EPS);
  float2 gq = ((const float2*)g)[cq];
  float2 beq = ((const float2*)be)[cq];
  float y0 = fmaxf(fmaf(d0 * rstd, gq.x, beq.x), 0.f);
  float y1 = fmaxf(fmaf(d1 * rstd, gq.y, beq.y), 0.f);
  if (lane < 16) ((float2*)h2)[(size_t)i * 16 + cq] = make_float2(y0, y1);
}

// ---------------- global mean pool: one block per graph, batch sorted ----------------
__global__ __launch_bounds__(256) void pool_kernel(const float* __restrict__ h2,
                                                   const int* __restrict__ batch,
                                                   float* __restrict__ out, int N) {
  int gidx = blockIdx.x;
  int a = 0, b = N;
  while (a < b) { int m = (a + b) >> 1; if (batch[m] < gidx) a = m + 1; else b = m; }
  int lo = a;
  b = N;
  while (a < b) { int m = (a + b) >> 1; if (batch[m] < gidx + 1) a = m + 1; else b = m; }
  int hi = a;
  int c = threadIdx.x & 31, r = threadIdx.x >> 5;
  float s = 0.f;
  for (int n = lo + r; n < hi; n += 8) s += h2[(size_t)n * 32 + c];
  __shared__ float buf[256];
  buf[threadIdx.x] = s;
  __syncthreads();
  if (threadIdx.x < 128) buf[threadIdx.x] += buf[threadIdx.x + 128];
  __syncthreads();
  if (threadIdx.x < 64) buf[threadIdx.x] += buf[threadIdx.x + 64];
  __syncthreads();
  if (threadIdx.x < 32) {
    float v = buf[threadIdx.x] + buf[threadIdx.x + 32];
    int cnt = hi - lo;
    out[gidx * 32 + threadIdx.x] = v / (float)(cnt > 0 ? cnt : 1);
  }
}

extern "C" void kernel_launch(void* const* d_in, const int* in_sizes, int n_in,
                              void* d_out, int out_size, void* d_ws, size_t ws_size,
                              hipStream_t stream) {
  const float* x    = (const float*)d_in[0];
  const int*   ei   = (const int*)d_in[1];
  const int*   batch= (const int*)d_in[2];
  const float* Wl1  = (const float*)d_in[3];
  const float* bl1  = (const float*)d_in[4];
  const float* Wr1  = (const float*)d_in[5];
  const float* br1  = (const float*)d_in[6];
  const float* att1 = (const float*)d_in[7];
  const float* b1   = (const float*)d_in[8];
  const float* ln1g = (const float*)d_in[9];
  const float* ln1b = (const float*)d_in[10];
  const float* Wl2  = (const float*)d_in[11];
  const float* bl2  = (const float*)d_in[12];
  const float* Wr2  = (const float*)d_in[13];
  const float* br2  = (const float*)d_in[14];
  const float* att2 = (const float*)d_in[15];
  const float* b2   = (const float*)d_in[16];
  const float* ln2g = (const float*)d_in[17];
  const float* ln2b = (const float*)d_in[18];

  int N = in_sizes[0] / 8;
  int E = in_sizes[1] / 2;
  int G = out_size / 32;

  char* ws = (char*)d_ws;
  size_t off = 0;
  auto alloc = [&](size_t bytes) -> void* {
    void* p = (void*)(ws + off);
    off += (bytes + 255) & ~(size_t)255;
    return p;
  };
  int*      cnt    = (int*)alloc((size_t)N * 4);
  int*      offs   = (int*)alloc((size_t)(N + 1) * 4);
  int*      cursor = (int*)alloc((size_t)N * 4);
  int*      esrc   = (int*)alloc((size_t)(E + N) * 4);
  uint32_t* xl1b   = (uint32_t*)alloc((size_t)N * 128 * 4);  // 256 bf16/row
  float*    xr1    = (float*)alloc((size_t)N * 256 * 4);
  uint32_t* h1b    = (uint32_t*)alloc((size_t)N * 64 * 2);   // 64 bf16/row
  uint16_t* Wtb    = (uint16_t*)alloc((size_t)256 * 64 * 2); // Wt[256][64] bf16
  uint32_t* xl2b   = (uint32_t*)alloc((size_t)N * 64 * 4);   // 128 bf16/row
  float*    xr2    = (float*)alloc((size_t)N * 128 * 4);
  float*    h2     = (float*)alloc((size_t)N * 32 * 4);

  int tot = E + N;
  zero_kernel<<<(N + 255) / 256, 256, 0, stream>>>(cnt, N);
  gemm1_hist_kernel<<<2048, 256, 0, stream>>>(x, Wl1, bl1, Wr1, br1, xl1b, xr1, N,
                                              ei, E, cnt);
  scan_kernel<<<1, 1024, 0, stream>>>(cnt, offs, cursor, N);
  scatter_kernel<<<(tot + 255) / 256, 256, 0, stream>>>(ei, E, N, cursor, esrc,
                                                        Wl2, Wr2, Wtb);

  attn1_kernel<<<(N + 3) / 4, 256, 0, stream>>>(xl1b, xr1, att1, b1, ln1g, ln1b,
                                                offs, esrc, h1b, N);
  gemm2_mfma_kernel<<<(N + 15) / 16, 256, 0, stream>>>((const uint16_t*)h1b, Wtb, bl2, br2,
                                                       xl2b, xr2, N);
  attn2_kernel<<<(N + 3) / 4, 256, 0, stream>>>(xl2b, xr2, att2, b2, ln2g, ln2b,
                                                offs, esrc, h2, N);

  pool_kernel<<<G, 256, 0, stream>>>(h2, batch, (float*)d_out, N);
}